// Round 20
// baseline (59.112 us; speedup 1.0000x reference)
//
#include <hip/hip_runtime.h>
#include <hip/hip_bf16.h>

typedef __attribute__((ext_vector_type(4))) int i32x4;

#define AS1 __attribute__((address_space(1)))
#define AS3 __attribute__((address_space(3)))

#define DDIM 512
#define BK 64

// ---------------- Kernel 1: normalize + pos-pair dot + int8 write --------------
// Wave-local: one wave per sample k, float4 loads, shuffle-only reduction.
__global__ __launch_bounds__(256) void norm_pd_kernel(
    const float* __restrict__ ei, const float* __restrict__ ej,
    unsigned char* __restrict__ zq, float* __restrict__ pd,
    float* __restrict__ rowsum, float* __restrict__ out, int N) {
  const int k = blockIdx.x * 4 + (threadIdx.x >> 6);
  const int l = threadIdx.x & 63;

  const float4 a0 = *reinterpret_cast<const float4*>(ei + (size_t)k * DDIM + l * 8);
  const float4 a1 = *reinterpret_cast<const float4*>(ei + (size_t)k * DDIM + l * 8 + 4);
  const float4 b0 = *reinterpret_cast<const float4*>(ej + (size_t)k * DDIM + l * 8);
  const float4 b1 = *reinterpret_cast<const float4*>(ej + (size_t)k * DDIM + l * 8 + 4);

  float sii = a0.x*a0.x + a0.y*a0.y + a0.z*a0.z + a0.w*a0.w
            + a1.x*a1.x + a1.y*a1.y + a1.z*a1.z + a1.w*a1.w;
  float sjj = b0.x*b0.x + b0.y*b0.y + b0.z*b0.z + b0.w*b0.w
            + b1.x*b1.x + b1.y*b1.y + b1.z*b1.z + b1.w*b1.w;
  float sij = a0.x*b0.x + a0.y*b0.y + a0.z*b0.z + a0.w*b0.w
            + a1.x*b1.x + a1.y*b1.y + a1.z*b1.z + a1.w*b1.w;
#pragma unroll
  for (int off = 32; off; off >>= 1) {
    sii += __shfl_xor(sii, off);
    sjj += __shfl_xor(sjj, off);
    sij += __shfl_xor(sij, off);
  }
  const float rsi = rsqrtf(sii), rsj = rsqrtf(sjj);

  unsigned char qa[8], qb[8];
  const float av[8] = {a0.x, a0.y, a0.z, a0.w, a1.x, a1.y, a1.z, a1.w};
  const float bv[8] = {b0.x, b0.y, b0.z, b0.w, b1.x, b1.y, b1.z, b1.w};
#pragma unroll
  for (int i = 0; i < 8; ++i) {
    qa[i] = (unsigned char)((int)rintf(127.0f * av[i] * rsi) & 0xff);
    qb[i] = (unsigned char)((int)rintf(127.0f * bv[i] * rsj) & 0xff);
  }
  *reinterpret_cast<uint2*>(zq + (size_t)k * DDIM + l * 8) =
      *reinterpret_cast<const uint2*>(qa);
  *reinterpret_cast<uint2*>(zq + (size_t)(N + k) * DDIM + l * 8) =
      *reinterpret_cast<const uint2*>(qb);
  if (l == 0) {
    pd[k] = sij * rsi * rsj;
    rowsum[k] = 0.0f;
    rowsum[N + k] = 0.0f;
    if (k == 0) out[0] = 0.0f;
  }
}

// ---------------- Kernel 2: 256x256-tile 8-wave int8 MFMA fused sim-GEMM -------
// Per-wave output 128x64 (acc[8][4]): LDS-reads/MFMA = 12/32 (vs 16/16 at
// 64x64/wave) and staged bytes per MFMA halve — attacks the measured ~26%
// MfmaUtil plateau whose binder is LDS-port + vector-mem traffic, not sync.
// Control flow = R9 verbatim: double-buffer, stage(t+1); vmcnt(4); bar;
// compute(t); bar. No sched fences, no setprio (m141/m190). 528 blocks
// (= 8*66) triangular with bijective XCD chunking. LDS chunk swizzle
// s=(g+(row>>1))&3 on pre-swizzled global source + ds_read (rule #21).

#define MFMAI8(A, B, C) __builtin_amdgcn_mfma_i32_16x16x64_i8((A), (B), (C), 0, 0, 0)

__global__ __launch_bounds__(512, 2) void simloss_main(
    const unsigned char* __restrict__ zq, float* __restrict__ rowsum, int nwg) {
  // ---- bijective XCD-chunk remap (nwg = 528 = 8*66, r8 = 0) ----
  const int orig = blockIdx.x;
  const int q = nwg >> 3, r8 = nwg & 7;
  const int xcd = orig & 7, pos0 = orig >> 3;
  const int t0 = (xcd < r8 ? xcd * (q + 1) : r8 * (q + 1) + (xcd - r8) * q) + pos0;

  // ---- triangular decode: t0 -> (bx, by), bx <= by ----
  const float ff = sqrtf(8.0f * (float)t0 + 1.0f);
  int by = (int)((ff - 1.0f) * 0.5f);
  while ((by + 1) * (by + 2) / 2 <= t0) ++by;
  while (by * (by + 1) / 2 > t0) --by;
  const int bx = t0 - by * (by + 1) / 2;

  const int row0 = bx * 256;
  const int col0 = by * 256;

  __shared__ unsigned char lds[2][2][16384];  // [buf][A,B][256 rows x 64 B]

  const int tid = threadIdx.x;
  const int w = tid >> 6;        // wave 0..7
  const int l = tid & 63;
  const int wm = w >> 2;         // 0..1: 128-row half
  const int wn = w & 3;          // 0..3: 64-col strip
  const int lrow = l & 15;
  const int g = l >> 4;          // lane chunk-group (16B of k)

  i32x4 acc[8][4] = {};

  // stage one K-slab pair (A+B panels, 4 loads/thread) into lds[buf]
  auto stage = [&](int buf, int k0) {
#pragma unroll
    for (int half = 0; half < 2; ++half) {
      const int baserow = half ? col0 : row0;
#pragma unroll
      for (int it = 0; it < 2; ++it) {
        const int pp = it * 512 + tid;        // 16B chunk id 0..1023
        const int row = pp >> 2;              // 0..255
        const int s = pp & 3;                 // stored chunk slot
        const int gs = (s - (row >> 1)) & 3;  // source chunk (swizzle inverse)
        const unsigned char* src = zq + (size_t)(baserow + row) * DDIM + k0 + gs * 16;
        char* dst = (char*)&lds[buf][half][0] + (unsigned)((it * 512 + w * 64) * 16);
        __builtin_amdgcn_global_load_lds((const AS1 void*)src, (AS3 void*)dst, 16, 0, 0);
      }
    }
  };

  auto compute = [&](int buf) {
    const unsigned char* ab = &lds[buf][0][0];
    const unsigned char* bb = &lds[buf][1][0];
    i32x4 Af[8], Bf[4];
#pragma unroll
    for (int mf = 0; mf < 8; ++mf) {
      const int rr = wm * 128 + mf * 16 + lrow;   // 0..255
      Af[mf] = *reinterpret_cast<const i32x4*>(ab + rr * 64 + (((g + (rr >> 1)) & 3) << 4));
    }
#pragma unroll
    for (int nf = 0; nf < 4; ++nf) {
      const int cc = wn * 64 + nf * 16 + lrow;    // 0..255
      Bf[nf] = *reinterpret_cast<const i32x4*>(bb + cc * 64 + (((g + (cc >> 1)) & 3) << 4));
    }
#pragma unroll
    for (int mf = 0; mf < 8; ++mf)
#pragma unroll
      for (int nf = 0; nf < 4; ++nf)
        acc[mf][nf] = MFMAI8(Af[mf], Bf[nf], acc[mf][nf]);
  };

  // ---- prologue ----
  stage(0, 0);

  // ---- K-loop: 8 tiles of BK=64, fully unrolled, static buffer indices ----
#pragma unroll
  for (int t = 0; t < 7; ++t) {
    const int buf = t & 1;
    stage(buf ^ 1, (t + 1) * BK);
    asm volatile("s_waitcnt vmcnt(4)" ::: "memory");  // tile t's 4 loads landed
    __builtin_amdgcn_s_barrier();
    compute(buf);
    __builtin_amdgcn_s_barrier();
  }
  asm volatile("s_waitcnt vmcnt(0)" ::: "memory");
  __builtin_amdgcn_s_barrier();
  compute(1);

  // ---- epilogue ----
  // C/D layout (16x16): col = l&15, row = (l>>4)*4 + reg
  const float SC = 2.0f * 1.44269504088896340736f / 16129.0f;  // 2*log2(e)/127^2
  const int lgrp = l >> 4;
  const int lcol = l & 15;

  float cs[4] = {0.0f, 0.0f, 0.0f, 0.0f};
#pragma unroll
  for (int mf = 0; mf < 8; ++mf) {
    float rs[4];
#pragma unroll
    for (int rg = 0; rg < 4; ++rg) rs[rg] = 0.0f;
#pragma unroll
    for (int nf = 0; nf < 4; ++nf) {
#pragma unroll
      for (int rg = 0; rg < 4; ++rg) {
        const float e = exp2f((float)acc[mf][nf][rg] * SC);
        rs[rg] += e;
        cs[nf] += e;
      }
    }
#pragma unroll
    for (int off = 1; off < 16; off <<= 1) {
#pragma unroll
      for (int rg = 0; rg < 4; ++rg) rs[rg] += __shfl_xor(rs[rg], off);
    }
    if (lcol == 0) {
      const int rowb = row0 + wm * 128 + mf * 16 + lgrp * 4;
#pragma unroll
      for (int rg = 0; rg < 4; ++rg) atomicAdd(&rowsum[rowb + rg], rs[rg]);
    }
  }

  // column sums (mirror) — off-diagonal tiles only; both wm halves contribute
  if (bx != by) {
#pragma unroll
    for (int nf = 0; nf < 4; ++nf) {
      float c = cs[nf];
      c += __shfl_xor(c, 16);
      c += __shfl_xor(c, 32);
      if (lgrp == 0) atomicAdd(&rowsum[col0 + wn * 64 + nf * 16 + lcol], c);
    }
  }
}

// ---------------- Kernel 3: finalize (parallel, atomic partials) ----------------
__global__ __launch_bounds__(1024) void finalize_kernel(
    const float* __restrict__ rowsum, const float* __restrict__ pd,
    float* __restrict__ out, int M, int N) {
  const int i = blockIdx.x * 1024 + threadIdx.x;
  const float E2 = 7.38905609893065f;  // exp(2) — diagonal term (unit rows)
  float acc = 0.0f;
  if (i < M) {
    const float denom = rowsum[i] - E2;
    const int kk = (i < N) ? i : (i - N);
    acc = logf(denom) - 2.0f * pd[kk];
  }
#pragma unroll
  for (int off = 32; off; off >>= 1) acc += __shfl_down(acc, off);
  __shared__ float red[16];
  const int t = threadIdx.x;
  if ((t & 63) == 0) red[t >> 6] = acc;
  __syncthreads();
  if (t < 64) {
    float s = (t < 16) ? red[t] : 0.0f;
#pragma unroll
    for (int off = 8; off; off >>= 1) s += __shfl_down(s, off);
    if (t == 0) atomicAdd(out, s / (float)M);
  }
}

extern "C" void kernel_launch(void* const* d_in, const int* in_sizes, int n_in,
                              void* d_out, int out_size, void* d_ws, size_t ws_size,
                              hipStream_t stream) {
  const float* ei = (const float*)d_in[0];
  const float* ej = (const float*)d_in[1];
  float* out = (float*)d_out;

  const int N = in_sizes[0] / DDIM;  // 4096
  const int M = 2 * N;               // 8192
  const int NT = M / 256;            // 32 tiles per dim
  const int NTRI = NT * (NT + 1) / 2;  // 528 blocks (= 8*66)

  char* ws = (char*)d_ws;
  unsigned char* zq = (unsigned char*)ws;                        // M * 512 i8
  float* pd = (float*)(ws + (size_t)M * DDIM);                   // N f32
  float* rowsum = (float*)(ws + (size_t)M * DDIM + (size_t)N * 4);  // M f32

  norm_pd_kernel<<<N / 4, 256, 0, stream>>>(ei, ej, zq, pd, rowsum, out, N);
  simloss_main<<<NTRI, 512, 0, stream>>>(zq, rowsum, NTRI);
  finalize_kernel<<<(M + 1023) / 1024, 1024, 0, stream>>>(rowsum, pd, out, M, N);
}

// Round 21
// 44.342 us; speedup vs baseline: 1.3331x; 1.3331x over previous
//
#include <hip/hip_runtime.h>
#include <hip/hip_bf16.h>

typedef __attribute__((ext_vector_type(4))) int i32x4;

#define AS1 __attribute__((address_space(1)))
#define AS3 __attribute__((address_space(3)))

#define DDIM 512
#define BK 64

// ---------------- Kernel 1: normalize + pos-pair dot + int8 write --------------
// Wave-local: one wave per sample k, float4 loads, shuffle-only reduction.
__global__ __launch_bounds__(256) void norm_pd_kernel(
    const float* __restrict__ ei, const float* __restrict__ ej,
    unsigned char* __restrict__ zq, float* __restrict__ pd,
    float* __restrict__ rowsum, float* __restrict__ out, int N) {
  const int k = blockIdx.x * 4 + (threadIdx.x >> 6);
  const int l = threadIdx.x & 63;

  const float4 a0 = *reinterpret_cast<const float4*>(ei + (size_t)k * DDIM + l * 8);
  const float4 a1 = *reinterpret_cast<const float4*>(ei + (size_t)k * DDIM + l * 8 + 4);
  const float4 b0 = *reinterpret_cast<const float4*>(ej + (size_t)k * DDIM + l * 8);
  const float4 b1 = *reinterpret_cast<const float4*>(ej + (size_t)k * DDIM + l * 8 + 4);

  float sii = a0.x*a0.x + a0.y*a0.y + a0.z*a0.z + a0.w*a0.w
            + a1.x*a1.x + a1.y*a1.y + a1.z*a1.z + a1.w*a1.w;
  float sjj = b0.x*b0.x + b0.y*b0.y + b0.z*b0.z + b0.w*b0.w
            + b1.x*b1.x + b1.y*b1.y + b1.z*b1.z + b1.w*b1.w;
  float sij = a0.x*b0.x + a0.y*b0.y + a0.z*b0.z + a0.w*b0.w
            + a1.x*b1.x + a1.y*b1.y + a1.z*b1.z + a1.w*b1.w;
#pragma unroll
  for (int off = 32; off; off >>= 1) {
    sii += __shfl_xor(sii, off);
    sjj += __shfl_xor(sjj, off);
    sij += __shfl_xor(sij, off);
  }
  const float rsi = rsqrtf(sii), rsj = rsqrtf(sjj);

  unsigned char qa[8], qb[8];
  const float av[8] = {a0.x, a0.y, a0.z, a0.w, a1.x, a1.y, a1.z, a1.w};
  const float bv[8] = {b0.x, b0.y, b0.z, b0.w, b1.x, b1.y, b1.z, b1.w};
#pragma unroll
  for (int i = 0; i < 8; ++i) {
    qa[i] = (unsigned char)((int)rintf(127.0f * av[i] * rsi) & 0xff);
    qb[i] = (unsigned char)((int)rintf(127.0f * bv[i] * rsj) & 0xff);
  }
  *reinterpret_cast<uint2*>(zq + (size_t)k * DDIM + l * 8) =
      *reinterpret_cast<const uint2*>(qa);
  *reinterpret_cast<uint2*>(zq + (size_t)(N + k) * DDIM + l * 8) =
      *reinterpret_cast<const uint2*>(qb);
  if (l == 0) {
    pd[k] = sij * rsi * rsj;
    rowsum[k] = 0.0f;
    rowsum[N + k] = 0.0f;
    if (k == 0) out[0] = 0.0f;
  }
}

// ---------------- Kernel 2: int8 MFMA fused sim-GEMM (measured optimum) --------
// 128x128 tile, 4 waves (64x64/wave), BK=64 -> ONE mfma_i32_16x16x64_i8 per
// (mf,nf) per K-tile. Double-buffered LDS (32 KiB), fully-unrolled K-loop,
// counted vmcnt(4) + raw barriers, NO sched fences/setprio (m141). 2080-block
// triangular dispatch with bijective XCD chunking. LDS chunk swizzle
// s=(g+(row>>1))&3 on pre-swizzled global source + ds_read (rule #21).
// Locked after 10 structural ablations (dtype/geometry/sync/occupancy/
// dispatch/pipeline-depth) all measured null or negative vs this config.

#define MFMAI8(A, B, C) __builtin_amdgcn_mfma_i32_16x16x64_i8((A), (B), (C), 0, 0, 0)

__global__ __launch_bounds__(256, 4) void simloss_main(
    const unsigned char* __restrict__ zq, float* __restrict__ rowsum, int nwg) {
  // ---- bijective XCD-chunk remap (nwg = 2080 = 8*260, r8 = 0) ----
  const int orig = blockIdx.x;
  const int q = nwg >> 3, r8 = nwg & 7;
  const int xcd = orig & 7, pos0 = orig >> 3;
  const int t0 = (xcd < r8 ? xcd * (q + 1) : r8 * (q + 1) + (xcd - r8) * q) + pos0;

  // ---- triangular decode: t0 -> (bx, by), bx <= by ----
  const float ff = sqrtf(8.0f * (float)t0 + 1.0f);
  int by = (int)((ff - 1.0f) * 0.5f);
  while ((by + 1) * (by + 2) / 2 <= t0) ++by;
  while (by * (by + 1) / 2 > t0) --by;
  const int bx = t0 - by * (by + 1) / 2;

  const int row0 = bx * 128;
  const int col0 = by * 128;

  __shared__ unsigned char lds[2][2][8192];  // [buf][A,B][128 rows x 64 B]

  const int tid = threadIdx.x;
  const int w = tid >> 6;        // wave 0..3
  const int l = tid & 63;
  const int wr = (w >> 1) * 64;  // wave row offset in tile
  const int wc = (w & 1) * 64;   // wave col offset in tile
  const int lrow = l & 15;
  const int g = l >> 4;          // lane chunk-group (16B of k)

  i32x4 acc[4][4] = {};

  // stage one K-slab pair (A+B panels, 4 loads/thread) into lds[buf]
  auto stage = [&](int buf, int k0) {
#pragma unroll
    for (int half = 0; half < 2; ++half) {
      const int baserow = half ? col0 : row0;
#pragma unroll
      for (int it = 0; it < 2; ++it) {
        const int pp = it * 256 + tid;        // 16B chunk id 0..511
        const int row = pp >> 2;              // 0..127
        const int s = pp & 3;                 // stored chunk slot
        const int gs = (s - (row >> 1)) & 3;  // source chunk (swizzle inverse)
        const unsigned char* src = zq + (size_t)(baserow + row) * DDIM + k0 + gs * 16;
        char* dst = (char*)&lds[buf][half][0] + (unsigned)((it * 256 + w * 64) * 16);
        __builtin_amdgcn_global_load_lds((const AS1 void*)src, (AS3 void*)dst, 16, 0, 0);
      }
    }
  };

  auto compute = [&](int buf) {
    const unsigned char* ab = &lds[buf][0][0];
    const unsigned char* bb = &lds[buf][1][0];
    i32x4 Af[4], Bf[4];
#pragma unroll
    for (int mf = 0; mf < 4; ++mf) {
      const int rr = wr + mf * 16 + lrow;
      Af[mf] = *reinterpret_cast<const i32x4*>(ab + rr * 64 + (((g + (rr >> 1)) & 3) << 4));
    }
#pragma unroll
    for (int nf = 0; nf < 4; ++nf) {
      const int cc = wc + nf * 16 + lrow;
      Bf[nf] = *reinterpret_cast<const i32x4*>(bb + cc * 64 + (((g + (cc >> 1)) & 3) << 4));
    }
#pragma unroll
    for (int mf = 0; mf < 4; ++mf)
#pragma unroll
      for (int nf = 0; nf < 4; ++nf)
        acc[mf][nf] = MFMAI8(Af[mf], Bf[nf], acc[mf][nf]);
  };

  // ---- prologue ----
  stage(0, 0);

  // ---- K-loop: 8 tiles of BK=64, fully unrolled, static buffer indices ----
#pragma unroll
  for (int t = 0; t < 7; ++t) {
    const int buf = t & 1;
    stage(buf ^ 1, (t + 1) * BK);
    asm volatile("s_waitcnt vmcnt(4)" ::: "memory");  // tile t's 4 loads landed
    __builtin_amdgcn_s_barrier();
    compute(buf);
    __builtin_amdgcn_s_barrier();
  }
  asm volatile("s_waitcnt vmcnt(0)" ::: "memory");
  __builtin_amdgcn_s_barrier();
  compute(1);

  // ---- epilogue ----
  // C/D layout (16x16): col = l&15, row = (l>>4)*4 + reg
  const float SC = 2.0f * 1.44269504088896340736f / 16129.0f;  // 2*log2(e)/127^2
  const int lgrp = l >> 4;
  const int lcol = l & 15;

  float e[4][4][4];
#pragma unroll
  for (int mf = 0; mf < 4; ++mf)
#pragma unroll
    for (int nf = 0; nf < 4; ++nf)
#pragma unroll
      for (int rg = 0; rg < 4; ++rg)
        e[mf][nf][rg] = exp2f((float)acc[mf][nf][rg] * SC);

  // row sums (this wave's 64 cols)
#pragma unroll
  for (int mf = 0; mf < 4; ++mf) {
    float rs[4];
#pragma unroll
    for (int rg = 0; rg < 4; ++rg) {
      float s = 0.0f;
#pragma unroll
      for (int nf = 0; nf < 4; ++nf) s += e[mf][nf][rg];
      rs[rg] = s;
    }
#pragma unroll
    for (int off = 1; off < 16; off <<= 1) {
#pragma unroll
      for (int rg = 0; rg < 4; ++rg) rs[rg] += __shfl_xor(rs[rg], off);
    }
    if (lcol == 0) {
      const int rowb = row0 + wr + mf * 16 + lgrp * 4;
#pragma unroll
      for (int rg = 0; rg < 4; ++rg) atomicAdd(&rowsum[rowb + rg], rs[rg]);
    }
  }

  // column sums (mirror) — off-diagonal tiles only
  if (bx != by) {
#pragma unroll
    for (int nf = 0; nf < 4; ++nf) {
      float cs = 0.0f;
#pragma unroll
      for (int mf = 0; mf < 4; ++mf)
#pragma unroll
        for (int rg = 0; rg < 4; ++rg) cs += e[mf][nf][rg];
      cs += __shfl_xor(cs, 16);
      cs += __shfl_xor(cs, 32);
      if (lgrp == 0) atomicAdd(&rowsum[col0 + wc + nf * 16 + lcol], cs);
    }
  }
}

// ---------------- Kernel 3: finalize (parallel, atomic partials) ----------------
__global__ __launch_bounds__(1024) void finalize_kernel(
    const float* __restrict__ rowsum, const float* __restrict__ pd,
    float* __restrict__ out, int M, int N) {
  const int i = blockIdx.x * 1024 + threadIdx.x;
  const float E2 = 7.38905609893065f;  // exp(2) — diagonal term (unit rows)
  float acc = 0.0f;
  if (i < M) {
    const float denom = rowsum[i] - E2;
    const int kk = (i < N) ? i : (i - N);
    acc = logf(denom) - 2.0f * pd[kk];
  }
#pragma unroll
  for (int off = 32; off; off >>= 1) acc += __shfl_down(acc, off);
  __shared__ float red[16];
  const int t = threadIdx.x;
  if ((t & 63) == 0) red[t >> 6] = acc;
  __syncthreads();
  if (t < 64) {
    float s = (t < 16) ? red[t] : 0.0f;
#pragma unroll
    for (int off = 8; off; off >>= 1) s += __shfl_down(s, off);
    if (t == 0) atomicAdd(out, s / (float)M);
  }
}

extern "C" void kernel_launch(void* const* d_in, const int* in_sizes, int n_in,
                              void* d_out, int out_size, void* d_ws, size_t ws_size,
                              hipStream_t stream) {
  const float* ei = (const float*)d_in[0];
  const float* ej = (const float*)d_in[1];
  float* out = (float*)d_out;

  const int N = in_sizes[0] / DDIM;  // 4096
  const int M = 2 * N;               // 8192
  const int NT = M / 128;            // 64 tiles per dim
  const int NTRI = NT * (NT + 1) / 2;  // 2080 blocks (= 8*260)

  char* ws = (char*)d_ws;
  unsigned char* zq = (unsigned char*)ws;                        // M * 512 i8
  float* pd = (float*)(ws + (size_t)M * DDIM);                   // N f32
  float* rowsum = (float*)(ws + (size_t)M * DDIM + (size_t)N * 4);  // M f32

  norm_pd_kernel<<<N / 4, 256, 0, stream>>>(ei, ej, zq, pd, rowsum, out, N);
  simloss_main<<<NTRI, 256, 0, stream>>>(zq, rowsum, NTRI);
  finalize_kernel<<<(M + 1023) / 1024, 1024, 0, stream>>>(rowsum, pd, out, M, N);
}